// Round 2
// baseline (428.981 us; speedup 1.0000x reference)
//
#include <hip/hip_runtime.h>
#include <hip/hip_bf16.h>

#define B_ 256
#define S_ 70
#define D_ 128
#define NSAMP 12

// ---------------- sess: masked mean of embedding[item] ----------------
__global__ __launch_bounds__(128) void sess_kernel(const int* __restrict__ item,
                                                   const int* __restrict__ mask,
                                                   const float* __restrict__ emb,
                                                   float* __restrict__ sess) {
    int b = blockIdx.x;
    int d = threadIdx.x;
    float acc = 0.f, msum = 0.f;
    for (int s = 0; s < S_; ++s) {
        int node = item[b * S_ + s];
        float m = (float)mask[b * S_ + s];
        acc += m * emb[(long)node * D_ + d];
        msum += m;
    }
    sess[b * D_ + d] = acc / msum;
}

// ---------------- h_local: masked multi-relation attention ----------------
#define ICHUNK 18
__global__ __launch_bounds__(256) void local_kernel(const int* __restrict__ inputs,
                                                    const int* __restrict__ adj,
                                                    const float* __restrict__ emb,
                                                    const float* __restrict__ a0,
                                                    const float* __restrict__ a1,
                                                    const float* __restrict__ a2,
                                                    const float* __restrict__ a3,
                                                    float* __restrict__ out) {
    __shared__ float h[S_][D_];      // 35840 B
    __shared__ float avec[4][D_];    // 2048 B
    __shared__ float e[S_];
    __shared__ float part[D_];

    int b = blockIdx.x;
    int chunk = blockIdx.y;
    int tid = threadIdx.x;
    int wave = tid >> 6, lane = tid & 63;

    // stage h[b] = embedding[inputs[b,:]] as float4
    for (int idx = tid; idx < S_ * (D_ / 4); idx += 256) {
        int s = idx >> 5, q = idx & 31;           // D_/4 = 32 float4 per row
        const float4* src = (const float4*)(emb + (long)inputs[b * S_ + s] * D_);
        ((float4*)h[s])[q] = src[q];
    }
    if (tid < D_) {
        avec[0][tid] = a0[tid];
        avec[1][tid] = a1[tid];
        avec[2][tid] = a2[tid];
        avec[3][tid] = a3[tid];
    }
    __syncthreads();

    int i0 = chunk * ICHUNK;
    int i1 = i0 + ICHUNK; if (i1 > S_) i1 = S_;

    for (int i = i0; i < i1; ++i) {
        // ---- scores e[j]: one wave per j, 64-lane dot over d ----
        for (int j = wave; j < S_; j += 4) {
            int a = adj[(long)b * S_ * S_ + i * S_ + j];   // wave-uniform
            float ev;
            if (a >= 1 && a <= 4) {
                const float* av = avec[a - 1];
                float p = h[i][lane]      * h[j][lane]      * av[lane]
                        + h[i][lane + 64] * h[j][lane + 64] * av[lane + 64];
                #pragma unroll
                for (int off = 32; off; off >>= 1) p += __shfl_xor(p, off);
                ev = p >= 0.f ? p : 0.2f * p;          // leaky_relu 0.2
            } else {
                ev = -9e15f;
            }
            if (lane == 0) e[j] = ev;
        }
        __syncthreads();

        // ---- softmax over j (wave 0) ----
        if (wave == 0) {
            float v0 = e[lane];                              // lane < 64 < S_
            float v1 = (lane + 64 < S_) ? e[lane + 64] : -INFINITY;
            float m = fmaxf(v0, v1);
            #pragma unroll
            for (int off = 32; off; off >>= 1) m = fmaxf(m, __shfl_xor(m, off));
            float s0 = expf(v0 - m);
            float s1 = (lane + 64 < S_) ? expf(v1 - m) : 0.f;
            float ss = s0 + s1;
            #pragma unroll
            for (int off = 32; off; off >>= 1) ss += __shfl_xor(ss, off);
            float inv = 1.f / ss;
            e[lane] = s0 * inv;
            if (lane + 64 < S_) e[lane + 64] = s1 * inv;
        }
        __syncthreads();

        // ---- h_local[i,d] = sum_j alpha[j] * h[j,d] ----
        {
            int d = tid & 127, half = tid >> 7;
            float acc = 0.f;
            int j0 = half * 35, j1 = j0 + 35;
            for (int j = j0; j < j1; ++j) acc += e[j] * h[j][d];
            if (half == 1) part[d] = acc;
            __syncthreads();
            if (half == 0)
                out[((long)b * S_ + i) * D_ + d] = acc + part[d];
            __syncthreads();   // protect e/part before next i
        }
    }
}

// ---------------- h_global: neighbor aggregation ----------------
__global__ __launch_bounds__(128) void global_kernel(const int* __restrict__ inputs,
                                                     const int* __restrict__ adj_all,
                                                     const float* __restrict__ num_w,
                                                     const float* __restrict__ emb,
                                                     const float* __restrict__ sess,
                                                     const float* __restrict__ gw1,
                                                     const float* __restrict__ gw2,
                                                     const float* __restrict__ gw3,
                                                     const float* __restrict__ gbias,
                                                     float* __restrict__ out) {
    __shared__ float nv[NSAMP][D_];        // neighbor embeddings
    __shared__ float feat[NSAMP][D_ + 1];  // sess*nv || nw
    __shared__ int   neigh[NSAMP];
    __shared__ float red2[NSAMP][2];
    __shared__ float cat[2 * D_];

    int bs = blockIdx.x;                   // b*S_ + s
    int b = bs / S_;
    int c = threadIdx.x;                   // output column / d index
    int lane = c & 63, wv = c >> 6;

    int node = inputs[bs];
    if (c < NSAMP) {
        neigh[c] = adj_all[(long)node * NSAMP + c];
        feat[c][D_] = num_w[(long)node * NSAMP + c];
    }
    __syncthreads();

    float sv = sess[b * D_ + c];
    #pragma unroll
    for (int k = 0; k < NSAMP; ++k) {
        float nvv = emb[(long)neigh[k] * D_ + c];
        nv[k][c] = nvv;
        feat[k][c] = sv * nvv;
    }
    __syncthreads();

    // al[k][c] = leaky_relu( sum_r feat[k][r] * gw1[r][c] )
    float acc[NSAMP];
    #pragma unroll
    for (int k = 0; k < NSAMP; ++k) acc[k] = 0.f;
    for (int r = 0; r <= D_; ++r) {        // 129 rows
        float g = gw1[r * D_ + c];
        #pragma unroll
        for (int k = 0; k < NSAMP; ++k) acc[k] += feat[k][r] * g;
    }

    // scores[k] = sum_c al[k][c] * gw2[c]
    float g2 = gw2[c];
    #pragma unroll
    for (int k = 0; k < NSAMP; ++k) {
        float al = acc[k] >= 0.f ? acc[k] : 0.2f * acc[k];
        float p = al * g2;
        #pragma unroll
        for (int off = 32; off; off >>= 1) p += __shfl_xor(p, off);
        if (lane == 0) red2[k][wv] = p;
    }
    __syncthreads();

    // softmax over k (redundant per thread) and nagg
    float w[NSAMP];
    float mx = -INFINITY;
    #pragma unroll
    for (int k = 0; k < NSAMP; ++k) { w[k] = red2[k][0] + red2[k][1]; mx = fmaxf(mx, w[k]); }
    float ssum = 0.f;
    #pragma unroll
    for (int k = 0; k < NSAMP; ++k) { w[k] = expf(w[k] - mx); ssum += w[k]; }
    float inv = 1.f / ssum;
    float nagg = 0.f;
    #pragma unroll
    for (int k = 0; k < NSAMP; ++k) nagg += (w[k] * inv) * nv[k][c];

    // cat = [h | nagg], out = relu(cat @ gw3 + gbias)
    cat[c] = emb[(long)node * D_ + c];
    cat[D_ + c] = nagg;
    __syncthreads();

    float o = gbias[c];
    for (int r = 0; r < 2 * D_; ++r) o += cat[r] * gw3[r * D_ + c];
    o = fmaxf(o, 0.f);

    out[(long)B_ * S_ * D_ + (long)bs * D_ + c] = o;
}

extern "C" void kernel_launch(void* const* d_in, const int* in_sizes, int n_in,
                              void* d_out, int out_size, void* d_ws, size_t ws_size,
                              hipStream_t stream) {
    const int*   inputs  = (const int*)  d_in[0];
    const int*   adj     = (const int*)  d_in[1];
    const int*   mask    = (const int*)  d_in[2];
    const int*   item    = (const int*)  d_in[3];
    // d_in[4] input_times: unused by the reference
    const int*   adj_all = (const int*)  d_in[5];
    const float* num_w   = (const float*)d_in[6];
    const float* emb     = (const float*)d_in[7];
    const float* a0      = (const float*)d_in[8];
    const float* a1      = (const float*)d_in[9];
    const float* a2      = (const float*)d_in[10];
    const float* a3      = (const float*)d_in[11];
    const float* gw1     = (const float*)d_in[12];
    const float* gw2     = (const float*)d_in[13];
    const float* gw3     = (const float*)d_in[14];
    const float* gbias   = (const float*)d_in[15];
    float* out = (float*)d_out;
    float* sess = (float*)d_ws;   // B_*D_ floats = 128 KiB

    sess_kernel<<<B_, D_, 0, stream>>>(item, mask, emb, sess);
    local_kernel<<<dim3(B_, 4), 256, 0, stream>>>(inputs, adj, emb, a0, a1, a2, a3, out);
    global_kernel<<<B_ * S_, D_, 0, stream>>>(inputs, adj_all, num_w, emb, sess,
                                              gw1, gw2, gw3, gbias, out);
}

// Round 3
// 230.030 us; speedup vs baseline: 1.8649x; 1.8649x over previous
//
#include <hip/hip_runtime.h>
#include <hip/hip_bf16.h>

#define B_ 256
#define S_ 70
#define D_ 128
#define NSAMP 12
#define GB 16               // graph positions (bs) per block in global kernel
#define NROW (GB * NSAMP)   // 192 feat rows per block
#define HGLOB (B_ * S_ * D_)

typedef float  f32x4 __attribute__((ext_vector_type(4)));
typedef short  s16x8 __attribute__((ext_vector_type(8)));

__device__ __forceinline__ unsigned short f2bf(float x) {
    union { float f; unsigned u; } v; v.f = x;
    return (unsigned short)((v.u + 0x7FFF + ((v.u >> 16) & 1)) >> 16);  // RNE
}

// ---------------- sess: masked mean of embedding[item] ----------------
__global__ __launch_bounds__(128) void sess_kernel(const int* __restrict__ item,
                                                   const int* __restrict__ mask,
                                                   const float* __restrict__ emb,
                                                   float* __restrict__ sess) {
    int b = blockIdx.x;
    int d = threadIdx.x;
    float acc = 0.f, msum = 0.f;
    for (int s = 0; s < S_; ++s) {
        int node = item[b * S_ + s];
        float m = (float)mask[b * S_ + s];
        acc += m * emb[(long)node * D_ + d];
        msum += m;
    }
    sess[b * D_ + d] = acc / msum;
}

// ---------------- pack gw1/gw3 transposed to bf16 ----------------
__global__ __launch_bounds__(256) void pack_weights(const float* __restrict__ gw1,
                                                    const float* __restrict__ gw3,
                                                    unsigned short* __restrict__ gw1T,
                                                    unsigned short* __restrict__ gw3T) {
    int idx = blockIdx.x * 256 + threadIdx.x;       // grid covers 128*256
    if (idx < 128 * 128) {                          // gw1T[c][r], r<128
        int c = idx >> 7, r = idx & 127;
        gw1T[idx] = f2bf(gw1[r * 128 + c]);
    }
    if (idx < 128 * 256) {                          // gw3T[c][r], r<256
        int c = idx >> 8, r = idx & 255;
        gw3T[idx] = f2bf(gw3[r * 128 + c]);
    }
}

// ---------------- h_local: masked multi-relation attention (unchanged) ----------------
#define ICHUNK 18
__global__ __launch_bounds__(256) void local_kernel(const int* __restrict__ inputs,
                                                    const int* __restrict__ adj,
                                                    const float* __restrict__ emb,
                                                    const float* __restrict__ a0,
                                                    const float* __restrict__ a1,
                                                    const float* __restrict__ a2,
                                                    const float* __restrict__ a3,
                                                    float* __restrict__ out) {
    __shared__ float h[S_][D_];
    __shared__ float avec[4][D_];
    __shared__ float e[S_];
    __shared__ float part[D_];

    int b = blockIdx.x;
    int chunk = blockIdx.y;
    int tid = threadIdx.x;
    int wave = tid >> 6, lane = tid & 63;

    for (int idx = tid; idx < S_ * (D_ / 4); idx += 256) {
        int s = idx >> 5, q = idx & 31;
        const float4* src = (const float4*)(emb + (long)inputs[b * S_ + s] * D_);
        ((float4*)h[s])[q] = src[q];
    }
    if (tid < D_) {
        avec[0][tid] = a0[tid];
        avec[1][tid] = a1[tid];
        avec[2][tid] = a2[tid];
        avec[3][tid] = a3[tid];
    }
    __syncthreads();

    int i0 = chunk * ICHUNK;
    int i1 = i0 + ICHUNK; if (i1 > S_) i1 = S_;

    for (int i = i0; i < i1; ++i) {
        for (int j = wave; j < S_; j += 4) {
            int a = adj[(long)b * S_ * S_ + i * S_ + j];
            float ev;
            if (a >= 1 && a <= 4) {
                const float* av = avec[a - 1];
                float p = h[i][lane]      * h[j][lane]      * av[lane]
                        + h[i][lane + 64] * h[j][lane + 64] * av[lane + 64];
                #pragma unroll
                for (int off = 32; off; off >>= 1) p += __shfl_xor(p, off);
                ev = p >= 0.f ? p : 0.2f * p;
            } else {
                ev = -9e15f;
            }
            if (lane == 0) e[j] = ev;
        }
        __syncthreads();

        if (wave == 0) {
            float v0 = e[lane];
            float v1 = (lane + 64 < S_) ? e[lane + 64] : -INFINITY;
            float m = fmaxf(v0, v1);
            #pragma unroll
            for (int off = 32; off; off >>= 1) m = fmaxf(m, __shfl_xor(m, off));
            float s0 = expf(v0 - m);
            float s1 = (lane + 64 < S_) ? expf(v1 - m) : 0.f;
            float ss = s0 + s1;
            #pragma unroll
            for (int off = 32; off; off >>= 1) ss += __shfl_xor(ss, off);
            float inv = 1.f / ss;
            e[lane] = s0 * inv;
            if (lane + 64 < S_) e[lane + 64] = s1 * inv;
        }
        __syncthreads();

        {
            int d = tid & 127, half = tid >> 7;
            float acc = 0.f;
            int j0 = half * 35, j1 = j0 + 35;
            for (int j = j0; j < j1; ++j) acc += e[j] * h[j][d];
            if (half == 1) part[d] = acc;
            __syncthreads();
            if (half == 0)
                out[((long)b * S_ + i) * D_ + d] = acc + part[d];
            __syncthreads();
        }
    }
}

// ---------------- h_global: MFMA neighbor aggregation, 16 bs per block ----------------
__global__ __launch_bounds__(256) void global_kernel(
        const int* __restrict__ inputs, const int* __restrict__ adj_all,
        const float* __restrict__ num_w, const float* __restrict__ emb,
        const float* __restrict__ sess,
        const unsigned short* __restrict__ gw1T, const float* __restrict__ gw1,
        const float* __restrict__ gw2,
        const unsigned short* __restrict__ gw3T, const float* __restrict__ gbias,
        float* __restrict__ out) {
    __shared__ unsigned short feat[NROW * 128];   // bf16, swizzled: 48 KiB
    __shared__ unsigned short cat[GB * 256];      // bf16, swizzled: 8 KiB
    __shared__ int   neigh[NROW];
    __shared__ float nw[NROW];
    __shared__ float spart[NROW][4];
    __shared__ float score[NROW];
    __shared__ float wsm[NROW];

    int tid  = threadIdx.x;
    int lane = tid & 63, wave = tid >> 6;
    int l15  = lane & 15, l4 = lane >> 4;
    int bs0  = blockIdx.x * GB;

    // ---- neighbor ids + weights ----
    if (tid < NROW) {
        int bsl = tid / NSAMP;
        int k   = tid - bsl * NSAMP;
        int node = inputs[bs0 + bsl];
        neigh[tid] = adj_all[node * NSAMP + k];
        nw[tid]    = num_w[node * NSAMP + k];
    }
    __syncthreads();

    // ---- stage feat = bf16(sess_b ⊙ emb[neigh]) swizzled ----
    // 192 rows × 16 chunks (8 bf16 each); chunk ^= (row&7)
    #pragma unroll
    for (int it = 0; it < (NROW * 16) / 256; ++it) {   // 12 iters
        int idx = it * 256 + tid;
        int row = idx >> 4, c8 = idx & 15;
        int bsl = row / NSAMP;
        int b   = (bs0 + bsl) / S_;
        const float4* ev = (const float4*)(emb + (long)neigh[row] * D_ + c8 * 8);
        float4 e0 = ev[0], e1 = ev[1];
        const float4* sv = (const float4*)(sess + b * D_ + c8 * 8);
        float4 s0 = sv[0], s1 = sv[1];
        s16x8 p;
        p[0] = (short)f2bf(e0.x * s0.x); p[1] = (short)f2bf(e0.y * s0.y);
        p[2] = (short)f2bf(e0.z * s0.z); p[3] = (short)f2bf(e0.w * s0.w);
        p[4] = (short)f2bf(e1.x * s1.x); p[5] = (short)f2bf(e1.y * s1.y);
        p[6] = (short)f2bf(e1.z * s1.z); p[7] = (short)f2bf(e1.w * s1.w);
        ((s16x8*)feat)[row * 16 + (c8 ^ (row & 7))] = p;
    }
    __syncthreads();

    // ---- gw1 matmul: (192×128) @ (128×128), wave handles N-tiles {2w, 2w+1} ----
    s16x8 bf[2][4];
    #pragma unroll
    for (int n = 0; n < 2; ++n) {
        int c = (wave * 2 + n) * 16 + l15;
        #pragma unroll
        for (int ks = 0; ks < 4; ++ks)
            bf[n][ks] = *(const s16x8*)(gw1T + c * 128 + ks * 32 + l4 * 8);
    }
    float g128a = gw1[128 * 128 + wave * 32 + l15];        // fp32 nw row
    float g128b = gw1[128 * 128 + wave * 32 + 16 + l15];
    float gw2a  = gw2[wave * 32 + l15];
    float gw2b  = gw2[wave * 32 + 16 + l15];

    for (int m = 0; m < NROW / 16; ++m) {                  // 12 M-tiles
        int arow = m * 16 + l15;
        s16x8 af[4];
        #pragma unroll
        for (int ks = 0; ks < 4; ++ks)
            af[ks] = ((s16x8*)feat)[arow * 16 + ((ks * 4 + l4) ^ (arow & 7))];

        f32x4 acc0 = {0.f, 0.f, 0.f, 0.f}, acc1 = {0.f, 0.f, 0.f, 0.f};
        #pragma unroll
        for (int ks = 0; ks < 4; ++ks) {
            acc0 = __builtin_amdgcn_mfma_f32_16x16x32_bf16(af[ks], bf[0][ks], acc0, 0, 0, 0);
            acc1 = __builtin_amdgcn_mfma_f32_16x16x32_bf16(af[ks], bf[1][ks], acc1, 0, 0, 0);
        }

        // epilogue: al = acc + nw*gw1[128], leaky, dot gw2, reduce over 16 cols
        float sp[4];
        #pragma unroll
        for (int reg = 0; reg < 4; ++reg) {
            int r = m * 16 + l4 * 4 + reg;
            float nwv = nw[r];
            float al0 = acc0[reg] + nwv * g128a;
            float al1 = acc1[reg] + nwv * g128b;
            al0 = al0 > 0.f ? al0 : 0.2f * al0;
            al1 = al1 > 0.f ? al1 : 0.2f * al1;
            sp[reg] = al0 * gw2a + al1 * gw2b;
        }
        #pragma unroll
        for (int off = 1; off < 16; off <<= 1) {
            #pragma unroll
            for (int reg = 0; reg < 4; ++reg) sp[reg] += __shfl_xor(sp[reg], off);
        }
        if (l15 == 0) {
            int rb = m * 16 + l4 * 4;
            #pragma unroll
            for (int reg = 0; reg < 4; ++reg) spart[rb + reg][wave] = sp[reg];
        }
    }
    __syncthreads();

    if (tid < NROW)
        score[tid] = spart[tid][0] + spart[tid][1] + spart[tid][2] + spart[tid][3];
    __syncthreads();

    // ---- softmax over k per bs ----
    if (tid < GB) {
        float mx = -1e30f;
        #pragma unroll
        for (int k = 0; k < NSAMP; ++k) mx = fmaxf(mx, score[tid * NSAMP + k]);
        float ex[NSAMP]; float ss = 0.f;
        #pragma unroll
        for (int k = 0; k < NSAMP; ++k) { ex[k] = expf(score[tid * NSAMP + k] - mx); ss += ex[k]; }
        float inv = 1.f / ss;
        #pragma unroll
        for (int k = 0; k < NSAMP; ++k) wsm[tid * NSAMP + k] = ex[k] * inv;
    }
    __syncthreads();

    // ---- nagg (fp32, emb re-read L2-hot) + cat staging (bf16 swizzled) ----
    {
        int bsl = tid >> 4;
        int c8  = tid & 15;          // 8-float chunk within 128
        float4 a0v = {0.f,0.f,0.f,0.f}, a1v = {0.f,0.f,0.f,0.f};
        #pragma unroll
        for (int k = 0; k < NSAMP; ++k) {
            float w = wsm[bsl * NSAMP + k];
            const float4* ev = (const float4*)(emb + (long)neigh[bsl * NSAMP + k] * D_ + c8 * 8);
            float4 e0 = ev[0], e1 = ev[1];
            a0v.x += w * e0.x; a0v.y += w * e0.y; a0v.z += w * e0.z; a0v.w += w * e0.w;
            a1v.x += w * e1.x; a1v.y += w * e1.y; a1v.z += w * e1.z; a1v.w += w * e1.w;
        }
        int node = inputs[bs0 + bsl];
        const float4* hv = (const float4*)(emb + (long)node * D_ + c8 * 8);
        float4 h0 = hv[0], h1 = hv[1];
        s16x8 ph, pa;
        ph[0]=(short)f2bf(h0.x); ph[1]=(short)f2bf(h0.y); ph[2]=(short)f2bf(h0.z); ph[3]=(short)f2bf(h0.w);
        ph[4]=(short)f2bf(h1.x); ph[5]=(short)f2bf(h1.y); ph[6]=(short)f2bf(h1.z); ph[7]=(short)f2bf(h1.w);
        pa[0]=(short)f2bf(a0v.x); pa[1]=(short)f2bf(a0v.y); pa[2]=(short)f2bf(a0v.z); pa[3]=(short)f2bf(a0v.w);
        pa[4]=(short)f2bf(a1v.x); pa[5]=(short)f2bf(a1v.y); pa[6]=(short)f2bf(a1v.z); pa[7]=(short)f2bf(a1v.w);
        int row = bsl;
        ((s16x8*)cat)[row * 32 + ( c8       ^ (row & 7))] = ph;   // h  -> k 0..127
        ((s16x8*)cat)[row * 32 + ((16 + c8) ^ (row & 7))] = pa;   // nagg -> k 128..255
    }
    __syncthreads();

    // ---- gw3 matmul: (16×256) @ (256×128) + bias + relu ----
    {
        f32x4 acc0 = {0.f,0.f,0.f,0.f}, acc1 = {0.f,0.f,0.f,0.f};
        int arow = l15;
        int cc = wave * 32 + l15;
        #pragma unroll
        for (int ks = 0; ks < 8; ++ks) {
            s16x8 a  = ((s16x8*)cat)[arow * 32 + ((ks * 4 + l4) ^ (arow & 7))];
            s16x8 b0 = *(const s16x8*)(gw3T +  cc       * 256 + ks * 32 + l4 * 8);
            s16x8 b1 = *(const s16x8*)(gw3T + (cc + 16) * 256 + ks * 32 + l4 * 8);
            acc0 = __builtin_amdgcn_mfma_f32_16x16x32_bf16(a, b0, acc0, 0, 0, 0);
            acc1 = __builtin_amdgcn_mfma_f32_16x16x32_bf16(a, b1, acc1, 0, 0, 0);
        }
        float gb0 = gbias[wave * 32 + l15];
        float gb1 = gbias[wave * 32 + 16 + l15];
        #pragma unroll
        for (int reg = 0; reg < 4; ++reg) {
            int bs = bs0 + l4 * 4 + reg;
            float o0 = acc0[reg] + gb0;
            float o1 = acc1[reg] + gb1;
            out[(long)HGLOB + (long)bs * D_ + wave * 32 + l15]      = o0 > 0.f ? o0 : 0.f;
            out[(long)HGLOB + (long)bs * D_ + wave * 32 + 16 + l15] = o1 > 0.f ? o1 : 0.f;
        }
    }
}

extern "C" void kernel_launch(void* const* d_in, const int* in_sizes, int n_in,
                              void* d_out, int out_size, void* d_ws, size_t ws_size,
                              hipStream_t stream) {
    const int*   inputs  = (const int*)  d_in[0];
    const int*   adj     = (const int*)  d_in[1];
    const int*   mask    = (const int*)  d_in[2];
    const int*   item    = (const int*)  d_in[3];
    const int*   adj_all = (const int*)  d_in[5];
    const float* num_w   = (const float*)d_in[6];
    const float* emb     = (const float*)d_in[7];
    const float* a0      = (const float*)d_in[8];
    const float* a1      = (const float*)d_in[9];
    const float* a2      = (const float*)d_in[10];
    const float* a3      = (const float*)d_in[11];
    const float* gw1     = (const float*)d_in[12];
    const float* gw2     = (const float*)d_in[13];
    const float* gw3     = (const float*)d_in[14];
    const float* gbias   = (const float*)d_in[15];
    float* out = (float*)d_out;

    float*          sess = (float*)d_ws;                              // 131072 B
    unsigned short* gw1T = (unsigned short*)((char*)d_ws + 131072);   // 32768 B
    unsigned short* gw3T = gw1T + 128 * 128;                          // 65536 B

    sess_kernel<<<B_, D_, 0, stream>>>(item, mask, emb, sess);
    pack_weights<<<128, 256, 0, stream>>>(gw1, gw3, gw1T, gw3T);
    local_kernel<<<dim3(B_, 4), 256, 0, stream>>>(inputs, adj, emb, a0, a1, a2, a3, out);
    global_kernel<<<(B_ * S_) / GB, 256, 0, stream>>>(inputs, adj_all, num_w, emb, sess,
                                                      gw1T, gw1, gw2, gw3T, gbias, out);
}

// Round 5
// 102.676 us; speedup vs baseline: 4.1780x; 2.2403x over previous
//
#include <hip/hip_runtime.h>
#include <hip/hip_bf16.h>

#define B_ 256
#define S_ 70
#define D_ 128
#define NSAMP 12
#define GB 16               // graph positions (bs) per block in global kernel
#define NROW (GB * NSAMP)   // 192 feat rows per block
#define HGLOB (B_ * S_ * D_)
#define IBLK 14             // i-rows per local block (5 blocks cover 70)
#define HTS 136             // HT row stride in shorts (272B = 68 dwords, 68%32=4 -> 2 lanes/bank)

typedef float  f32x4 __attribute__((ext_vector_type(4)));
typedef short  s16x8 __attribute__((ext_vector_type(8)));

__device__ __forceinline__ unsigned short f2bf(float x) {
    union { float f; unsigned u; } v; v.f = x;
    return (unsigned short)((v.u + 0x7FFF + ((v.u >> 16) & 1)) >> 16);  // RNE
}
__device__ __forceinline__ float bf2f(unsigned short u) {
    union { unsigned u; float f; } v; v.u = ((unsigned)u) << 16;
    return v.f;
}

// ---------------- sess: masked mean of embedding[item] ----------------
__global__ __launch_bounds__(128) void sess_kernel(const int* __restrict__ item,
                                                   const int* __restrict__ mask,
                                                   const float* __restrict__ emb,
                                                   float* __restrict__ sess) {
    int b = blockIdx.x;
    int d = threadIdx.x;
    float acc = 0.f, msum = 0.f;
    for (int s = 0; s < S_; ++s) {
        int node = item[b * S_ + s];
        float m = (float)mask[b * S_ + s];
        acc += m * emb[(long)node * D_ + d];
        msum += m;
    }
    sess[b * D_ + d] = acc / msum;
}

// ---------------- pack gw1/gw3 transposed to bf16 ----------------
__global__ __launch_bounds__(256) void pack_weights(const float* __restrict__ gw1,
                                                    const float* __restrict__ gw3,
                                                    unsigned short* __restrict__ gw1T,
                                                    unsigned short* __restrict__ gw3T) {
    int idx = blockIdx.x * 256 + threadIdx.x;       // grid covers 128*256
    if (idx < 128 * 128) {                          // gw1T[c][r], r<128
        int c = idx >> 7, r = idx & 127;
        gw1T[idx] = f2bf(gw1[r * 128 + c]);
    }
    if (idx < 128 * 256) {                          // gw3T[c][r], r<256
        int c = idx >> 8, r = idx & 255;
        gw3T[idx] = f2bf(gw3[r * 128 + c]);
    }
}

// ---------------- h_local: MFMA multi-relation attention ----------------
__global__ __launch_bounds__(256) void local_kernel(const int* __restrict__ inputs,
                                                    const int* __restrict__ adj,
                                                    const float* __restrict__ emb,
                                                    const float* __restrict__ a0p,
                                                    const float* __restrict__ a1p,
                                                    const float* __restrict__ a2p,
                                                    const float* __restrict__ a3p,
                                                    float* __restrict__ out) {
    __shared__ __align__(16) unsigned short hl[72 * 128];   // H bf16, chunk swz ^(row&7): 18 KB
    __shared__ __align__(16) unsigned short HT[128 * HTS];  // H^T bf16, identity layout: 34 KB
    __shared__ __align__(16) float          El[16 * 84];    // selected scores fp32: 5.4 KB
    __shared__ __align__(16) unsigned short al[16 * 104];   // alpha bf16, K zero-padded: 3.3 KB
    __shared__ int ids[S_];

    const int b  = blockIdx.x;
    const int i0 = blockIdx.y * IBLK;
    const int tid  = threadIdx.x;
    const int lane = tid & 63, wave = tid >> 6;
    const int l15  = lane & 15, l4 = lane >> 4;

    const s16x8 zero8 = {0, 0, 0, 0, 0, 0, 0, 0};

    // ---- phase A: node ids + zero padding regions ----
    if (tid < S_) ids[tid] = inputs[b * S_ + tid];
    for (int c = tid; c < (128 * HTS) / 8; c += 256) ((s16x8*)HT)[c] = zero8;
    if (tid < 32) ((s16x8*)hl)[70 * 16 + tid] = zero8;      // H rows 70,71
    __syncthreads();

    // ---- phase B: stage H (swizzled) + HT (identity scatter, stride HTS) ----
    #pragma unroll
    for (int it = 0; it < 5; ++it) {
        int idx = it * 256 + tid;
        if (idx < S_ * 16) {
            int s = idx >> 4, c8 = idx & 15;
            const float4* ev = (const float4*)(emb + (long)ids[s] * D_ + c8 * 8);
            float4 e0 = ev[0], e1 = ev[1];
            s16x8 p;
            p[0] = (short)f2bf(e0.x); p[1] = (short)f2bf(e0.y);
            p[2] = (short)f2bf(e0.z); p[3] = (short)f2bf(e0.w);
            p[4] = (short)f2bf(e1.x); p[5] = (short)f2bf(e1.y);
            p[6] = (short)f2bf(e1.z); p[7] = (short)f2bf(e1.w);
            ((s16x8*)hl)[s * 16 + (c8 ^ (s & 7))] = p;
            #pragma unroll
            for (int e = 0; e < 8; ++e) {
                int d = c8 * 8 + e;
                HT[d * HTS + s] = (unsigned short)p[e];
            }
        }
    }
    __syncthreads();

    // ---- phase C: E tiles (4 relations via MFMA), select by adj ----
    s16x8 af_all[4][4];                                     // [rel][ks]
    {
        const float* aptr[4] = {a0p, a1p, a2p, a3p};
        int hrow = i0 + l15;                                // <= 71, padded rows are 0
        #pragma unroll
        for (int ks = 0; ks < 4; ++ks) {
            s16x8 hf = ((s16x8*)hl)[hrow * 16 + ((ks * 4 + l4) ^ (hrow & 7))];
            #pragma unroll
            for (int r = 0; r < 4; ++r) {
                const float* ar = aptr[r];
                float4 alo = *(const float4*)(ar + ks * 32 + l4 * 8);
                float4 ahi = *(const float4*)(ar + ks * 32 + l4 * 8 + 4);
                s16x8 o;
                o[0] = (short)f2bf(bf2f((unsigned short)hf[0]) * alo.x);
                o[1] = (short)f2bf(bf2f((unsigned short)hf[1]) * alo.y);
                o[2] = (short)f2bf(bf2f((unsigned short)hf[2]) * alo.z);
                o[3] = (short)f2bf(bf2f((unsigned short)hf[3]) * alo.w);
                o[4] = (short)f2bf(bf2f((unsigned short)hf[4]) * ahi.x);
                o[5] = (short)f2bf(bf2f((unsigned short)hf[5]) * ahi.y);
                o[6] = (short)f2bf(bf2f((unsigned short)hf[6]) * ahi.z);
                o[7] = (short)f2bf(bf2f((unsigned short)hf[7]) * ahi.w);
                af_all[r][ks] = o;
            }
        }
    }

    for (int n = wave; n < 5; n += 4) {                     // 5 N-tiles over 4 waves
        s16x8 bfr[4];
        int jr = n * 16 + l15;
        int jrc = jr < 72 ? jr : 71;                        // clamp into zero-padded H
        #pragma unroll
        for (int ks = 0; ks < 4; ++ks)
            bfr[ks] = ((s16x8*)hl)[jrc * 16 + ((ks * 4 + l4) ^ (jrc & 7))];

        f32x4 ac0 = {0.f,0.f,0.f,0.f}, ac1 = {0.f,0.f,0.f,0.f};
        f32x4 ac2 = {0.f,0.f,0.f,0.f}, ac3 = {0.f,0.f,0.f,0.f};
        #pragma unroll
        for (int ks = 0; ks < 4; ++ks) {
            ac0 = __builtin_amdgcn_mfma_f32_16x16x32_bf16(af_all[0][ks], bfr[ks], ac0, 0, 0, 0);
            ac1 = __builtin_amdgcn_mfma_f32_16x16x32_bf16(af_all[1][ks], bfr[ks], ac1, 0, 0, 0);
            ac2 = __builtin_amdgcn_mfma_f32_16x16x32_bf16(af_all[2][ks], bfr[ks], ac2, 0, 0, 0);
            ac3 = __builtin_amdgcn_mfma_f32_16x16x32_bf16(af_all[3][ks], bfr[ks], ac3, 0, 0, 0);
        }

        #pragma unroll
        for (int reg = 0; reg < 4; ++reg) {
            int il = l4 * 4 + reg;                          // tile row 0..15
            int i  = i0 + il;
            int j  = n * 16 + l15;
            float v;
            if (j < S_) {
                int ic = i < S_ ? i : S_ - 1;               // clamp (pad rows discarded)
                int a  = adj[((long)b * S_ + ic) * S_ + j];
                float raw = (a == 1) ? ac0[reg] : (a == 2) ? ac1[reg]
                          : (a == 3) ? ac2[reg] : (a == 4) ? ac3[reg] : 0.f;
                v = (a >= 1 && a <= 4) ? (raw > 0.f ? raw : 0.2f * raw) : -9e15f;
            } else {
                v = -INFINITY;                              // j-padding, excluded
            }
            El[il * 84 + j] = v;
        }
    }
    __syncthreads();

    // ---- phase D: row softmax (16-lane group per row) + pack alpha bf16 ----
    {
        int g = tid >> 4, li = tid & 15;                    // 16 groups x 16 lanes
        float mx = -INFINITY;
        for (int j = li; j < S_; j += 16) mx = fmaxf(mx, El[g * 84 + j]);
        #pragma unroll
        for (int o = 1; o < 16; o <<= 1) mx = fmaxf(mx, __shfl_xor(mx, o));
        float sm = 0.f;
        for (int j = li; j < S_; j += 16) {
            float ex = __expf(El[g * 84 + j] - mx);
            El[g * 84 + j] = ex;
            sm += ex;
        }
        #pragma unroll
        for (int o = 1; o < 16; o <<= 1) sm += __shfl_xor(sm, o);
        float inv = 1.f / sm;
        for (int j = li; j < 104; j += 16)
            al[g * 104 + j] = (j < S_) ? f2bf(El[g * 84 + j] * inv) : (unsigned short)0;
    }
    __syncthreads();

    // ---- phase E: h_local = alpha @ H via HT ----
    for (int n = wave; n < 8; n += 4) {                     // 8 d-tiles over 4 waves
        f32x4 acc = {0.f, 0.f, 0.f, 0.f};
        int d = n * 16 + l15;
        #pragma unroll
        for (int ks = 0; ks < 3; ++ks) {                    // K = 96 (alpha zero >= 70)
            s16x8 afp = *(const s16x8*)(al + l15 * 104 + ks * 32 + l4 * 8);
            s16x8 bfp = *(const s16x8*)(HT + d * HTS + ks * 32 + l4 * 8);
            acc = __builtin_amdgcn_mfma_f32_16x16x32_bf16(afp, bfp, acc, 0, 0, 0);
        }
        #pragma unroll
        for (int reg = 0; reg < 4; ++reg) {
            int il = l4 * 4 + reg;
            if (il < IBLK)
                out[((long)b * S_ + (i0 + il)) * D_ + d] = acc[reg];
        }
    }
}

// ---------------- h_global: MFMA neighbor aggregation, 16 bs per block ----------------
__global__ __launch_bounds__(256) void global_kernel(
        const int* __restrict__ inputs, const int* __restrict__ adj_all,
        const float* __restrict__ num_w, const float* __restrict__ emb,
        const float* __restrict__ sess,
        const unsigned short* __restrict__ gw1T, const float* __restrict__ gw1,
        const float* __restrict__ gw2,
        const unsigned short* __restrict__ gw3T, const float* __restrict__ gbias,
        float* __restrict__ out) {
    __shared__ unsigned short feat[NROW * 128];   // bf16, swizzled: 48 KiB
    __shared__ unsigned short cat[GB * 256];      // bf16, swizzled: 8 KiB
    __shared__ int   neigh[NROW];
    __shared__ float nw[NROW];
    __shared__ float spart[NROW][4];
    __shared__ float score[NROW];
    __shared__ float wsm[NROW];

    int tid  = threadIdx.x;
    int lane = tid & 63, wave = tid >> 6;
    int l15  = lane & 15, l4 = lane >> 4;
    int bs0  = blockIdx.x * GB;

    if (tid < NROW) {
        int bsl = tid / NSAMP;
        int k   = tid - bsl * NSAMP;
        int node = inputs[bs0 + bsl];
        neigh[tid] = adj_all[node * NSAMP + k];
        nw[tid]    = num_w[node * NSAMP + k];
    }
    __syncthreads();

    #pragma unroll
    for (int it = 0; it < (NROW * 16) / 256; ++it) {   // 12 iters
        int idx = it * 256 + tid;
        int row = idx >> 4, c8 = idx & 15;
        int bsl = row / NSAMP;
        int b   = (bs0 + bsl) / S_;
        const float4* ev = (const float4*)(emb + (long)neigh[row] * D_ + c8 * 8);
        float4 e0 = ev[0], e1 = ev[1];
        const float4* sv = (const float4*)(sess + b * D_ + c8 * 8);
        float4 s0 = sv[0], s1 = sv[1];
        s16x8 p;
        p[0] = (short)f2bf(e0.x * s0.x); p[1] = (short)f2bf(e0.y * s0.y);
        p[2] = (short)f2bf(e0.z * s0.z); p[3] = (short)f2bf(e0.w * s0.w);
        p[4] = (short)f2bf(e1.x * s1.x); p[5] = (short)f2bf(e1.y * s1.y);
        p[6] = (short)f2bf(e1.z * s1.z); p[7] = (short)f2bf(e1.w * s1.w);
        ((s16x8*)feat)[row * 16 + (c8 ^ (row & 7))] = p;
    }
    __syncthreads();

    s16x8 bf[2][4];
    #pragma unroll
    for (int n = 0; n < 2; ++n) {
        int c = (wave * 2 + n) * 16 + l15;
        #pragma unroll
        for (int ks = 0; ks < 4; ++ks)
            bf[n][ks] = *(const s16x8*)(gw1T + c * 128 + ks * 32 + l4 * 8);
    }
    float g128a = gw1[128 * 128 + wave * 32 + l15];
    float g128b = gw1[128 * 128 + wave * 32 + 16 + l15];
    float gw2a  = gw2[wave * 32 + l15];
    float gw2b  = gw2[wave * 32 + 16 + l15];

    for (int m = 0; m < NROW / 16; ++m) {
        int arow = m * 16 + l15;
        s16x8 af[4];
        #pragma unroll
        for (int ks = 0; ks < 4; ++ks)
            af[ks] = ((s16x8*)feat)[arow * 16 + ((ks * 4 + l4) ^ (arow & 7))];

        f32x4 acc0 = {0.f, 0.f, 0.f, 0.f}, acc1 = {0.f, 0.f, 0.f, 0.f};
        #pragma unroll
        for (int ks = 0; ks < 4; ++ks) {
            acc0 = __builtin_amdgcn_mfma_f32_16x16x32_bf16(af[ks], bf[0][ks], acc0, 0, 0, 0);
            acc1 = __builtin_amdgcn_mfma_f32_16x16x32_bf16(af[ks], bf[1][ks], acc1, 0, 0, 0);
        }

        float sp[4];
        #pragma unroll
        for (int reg = 0; reg < 4; ++reg) {
            int r = m * 16 + l4 * 4 + reg;
            float nwv = nw[r];
            float al0 = acc0[reg] + nwv * g128a;
            float al1 = acc1[reg] + nwv * g128b;
            al0 = al0 > 0.f ? al0 : 0.2f * al0;
            al1 = al1 > 0.f ? al1 : 0.2f * al1;
            sp[reg] = al0 * gw2a + al1 * gw2b;
        }
        #pragma unroll
        for (int off = 1; off < 16; off <<= 1) {
            #pragma unroll
            for (int reg = 0; reg < 4; ++reg) sp[reg] += __shfl_xor(sp[reg], off);
        }
        if (l15 == 0) {
            int rb = m * 16 + l4 * 4;
            #pragma unroll
            for (int reg = 0; reg < 4; ++reg) spart[rb + reg][wave] = sp[reg];
        }
    }
    __syncthreads();

    if (tid < NROW)
        score[tid] = spart[tid][0] + spart[tid][1] + spart[tid][2] + spart[tid][3];
    __syncthreads();

    if (tid < GB) {
        float mx = -1e30f;
        #pragma unroll
        for (int k = 0; k < NSAMP; ++k) mx = fmaxf(mx, score[tid * NSAMP + k]);
        float ex[NSAMP]; float ss = 0.f;
        #pragma unroll
        for (int k = 0; k < NSAMP; ++k) { ex[k] = __expf(score[tid * NSAMP + k] - mx); ss += ex[k]; }
        float inv = 1.f / ss;
        #pragma unroll
        for (int k = 0; k < NSAMP; ++k) wsm[tid * NSAMP + k] = ex[k] * inv;
    }
    __syncthreads();

    {
        int bsl = tid >> 4;
        int c8  = tid & 15;
        float4 a0v = {0.f,0.f,0.f,0.f}, a1v = {0.f,0.f,0.f,0.f};
        #pragma unroll
        for (int k = 0; k < NSAMP; ++k) {
            float w = wsm[bsl * NSAMP + k];
            const float4* ev = (const float4*)(emb + (long)neigh[bsl * NSAMP + k] * D_ + c8 * 8);
            float4 e0 = ev[0], e1 = ev[1];
            a0v.x += w * e0.x; a0v.y += w * e0.y; a0v.z += w * e0.z; a0v.w += w * e0.w;
            a1v.x += w * e1.x; a1v.y += w * e1.y; a1v.z += w * e1.z; a1v.w += w * e1.w;
        }
        int node = inputs[bs0 + bsl];
        const float4* hv = (const float4*)(emb + (long)node * D_ + c8 * 8);
        float4 h0 = hv[0], h1 = hv[1];
        s16x8 ph, pa;
        ph[0]=(short)f2bf(h0.x); ph[1]=(short)f2bf(h0.y); ph[2]=(short)f2bf(h0.z); ph[3]=(short)f2bf(h0.w);
        ph[4]=(short)f2bf(h1.x); ph[5]=(short)f2bf(h1.y); ph[6]=(short)f2bf(h1.z); ph[7]=(short)f2bf(h1.w);
        pa[0]=(short)f2bf(a0v.x); pa[1]=(short)f2bf(a0v.y); pa[2]=(short)f2bf(a0v.z); pa[3]=(short)f2bf(a0v.w);
        pa[4]=(short)f2bf(a1v.x); pa[5]=(short)f2bf(a1v.y); pa[6]=(short)f2bf(a1v.z); pa[7]=(short)f2bf(a1v.w);
        int row = bsl;
        ((s16x8*)cat)[row * 32 + ( c8       ^ (row & 7))] = ph;
        ((s16x8*)cat)[row * 32 + ((16 + c8) ^ (row & 7))] = pa;
    }
    __syncthreads();

    {
        f32x4 acc0 = {0.f,0.f,0.f,0.f}, acc1 = {0.f,0.f,0.f,0.f};
        int arow = l15;
        int cc = wave * 32 + l15;
        #pragma unroll
        for (int ks = 0; ks < 8; ++ks) {
            s16x8 a  = ((s16x8*)cat)[arow * 32 + ((ks * 4 + l4) ^ (arow & 7))];
            s16x8 b0 = *(const s16x8*)(gw3T +  cc       * 256 + ks * 32 + l4 * 8);
            s16x8 b1 = *(const s16x8*)(gw3T + (cc + 16) * 256 + ks * 32 + l4 * 8);
            acc0 = __builtin_amdgcn_mfma_f32_16x16x32_bf16(a, b0, acc0, 0, 0, 0);
            acc1 = __builtin_amdgcn_mfma_f32_16x16x32_bf16(a, b1, acc1, 0, 0, 0);
        }
        float gb0 = gbias[wave * 32 + l15];
        float gb1 = gbias[wave * 32 + 16 + l15];
        #pragma unroll
        for (int reg = 0; reg < 4; ++reg) {
            int bs = bs0 + l4 * 4 + reg;
            float o0 = acc0[reg] + gb0;
            float o1 = acc1[reg] + gb1;
            out[(long)HGLOB + (long)bs * D_ + wave * 32 + l15]      = o0 > 0.f ? o0 : 0.f;
            out[(long)HGLOB + (long)bs * D_ + wave * 32 + 16 + l15] = o1 > 0.f ? o1 : 0.f;
        }
    }
}

extern "C" void kernel_launch(void* const* d_in, const int* in_sizes, int n_in,
                              void* d_out, int out_size, void* d_ws, size_t ws_size,
                              hipStream_t stream) {
    const int*   inputs  = (const int*)  d_in[0];
    const int*   adj     = (const int*)  d_in[1];
    const int*   mask    = (const int*)  d_in[2];
    const int*   item    = (const int*)  d_in[3];
    const int*   adj_all = (const int*)  d_in[5];
    const float* num_w   = (const float*)d_in[6];
    const float* emb     = (const float*)d_in[7];
    const float* a0      = (const float*)d_in[8];
    const float* a1      = (const float*)d_in[9];
    const float* a2      = (const float*)d_in[10];
    const float* a3      = (const float*)d_in[11];
    const float* gw1     = (const float*)d_in[12];
    const float* gw2     = (const float*)d_in[13];
    const float* gw3     = (const float*)d_in[14];
    const float* gbias   = (const float*)d_in[15];
    float* out = (float*)d_out;

    float*          sess = (float*)d_ws;                              // 131072 B
    unsigned short* gw1T = (unsigned short*)((char*)d_ws + 131072);   // 32768 B
    unsigned short* gw3T = gw1T + 128 * 128;                          // 65536 B

    sess_kernel<<<B_, D_, 0, stream>>>(item, mask, emb, sess);
    pack_weights<<<128, 256, 0, stream>>>(gw1, gw3, gw1T, gw3T);
    local_kernel<<<dim3(B_, 5), 256, 0, stream>>>(inputs, adj, emb, a0, a1, a2, a3, out);
    global_kernel<<<(B_ * S_) / GB, 256, 0, stream>>>(inputs, adj_all, num_w, emb, sess,
                                                      gw1T, gw1, gw2, gw3T, gbias, out);
}

// Round 6
// 97.671 us; speedup vs baseline: 4.3921x; 1.0512x over previous
//
#include <hip/hip_runtime.h>
#include <hip/hip_bf16.h>

#define B_ 256
#define S_ 70
#define D_ 128
#define NSAMP 12
#define HGLOB (B_ * S_ * D_)
#define IBLK 14             // i-rows per local block (5 blocks cover 70)
#define HTS 136             // HT row stride in shorts
#define NPOS 10             // s-positions per global block (7 blocks cover 70)
#define NR2 (NPOS * NSAMP)  // 120 neighbor rows
#define NRP 128             // padded to 8 M-tiles

typedef float  f32x4 __attribute__((ext_vector_type(4)));
typedef short  s16x8 __attribute__((ext_vector_type(8)));

__device__ __forceinline__ unsigned short f2bf(float x) {
    union { float f; unsigned u; } v; v.f = x;
    return (unsigned short)((v.u + 0x7FFF + ((v.u >> 16) & 1)) >> 16);  // RNE
}
__device__ __forceinline__ float bf2f(unsigned short u) {
    union { unsigned u; float f; } v; v.u = ((unsigned)u) << 16;
    return v.f;
}

// ---------------- sess: masked mean of embedding[item] ----------------
__global__ __launch_bounds__(128) void sess_kernel(const int* __restrict__ item,
                                                   const int* __restrict__ mask,
                                                   const float* __restrict__ emb,
                                                   float* __restrict__ sess) {
    int b = blockIdx.x;
    int d = threadIdx.x;
    float acc = 0.f, msum = 0.f;
    for (int s = 0; s < S_; ++s) {
        int node = item[b * S_ + s];
        float m = (float)mask[b * S_ + s];
        acc += m * emb[(long)node * D_ + d];
        msum += m;
    }
    sess[b * D_ + d] = acc / msum;
}

// ---------------- pack gw1/gw3 transposed to bf16 ----------------
__global__ __launch_bounds__(256) void pack_weights(const float* __restrict__ gw1,
                                                    const float* __restrict__ gw3,
                                                    unsigned short* __restrict__ gw1T,
                                                    unsigned short* __restrict__ gw3T) {
    int idx = blockIdx.x * 256 + threadIdx.x;       // grid covers 128*256
    if (idx < 128 * 128) {                          // gw1T[c][r], r<128
        int c = idx >> 7, r = idx & 127;
        gw1T[idx] = f2bf(gw1[r * 128 + c]);
    }
    if (idx < 128 * 256) {                          // gw3T[c][r], r<256
        int c = idx >> 8, r = idx & 255;
        gw3T[idx] = f2bf(gw3[r * 128 + c]);
    }
}

// ---------------- h_local: MFMA multi-relation attention (unchanged) ----------------
__global__ __launch_bounds__(256) void local_kernel(const int* __restrict__ inputs,
                                                    const int* __restrict__ adj,
                                                    const float* __restrict__ emb,
                                                    const float* __restrict__ a0p,
                                                    const float* __restrict__ a1p,
                                                    const float* __restrict__ a2p,
                                                    const float* __restrict__ a3p,
                                                    float* __restrict__ out) {
    __shared__ __align__(16) unsigned short hl[72 * 128];
    __shared__ __align__(16) unsigned short HT[128 * HTS];
    __shared__ __align__(16) float          El[16 * 84];
    __shared__ __align__(16) unsigned short al[16 * 104];
    __shared__ int ids[S_];

    const int b  = blockIdx.x;
    const int i0 = blockIdx.y * IBLK;
    const int tid  = threadIdx.x;
    const int lane = tid & 63, wave = tid >> 6;
    const int l15  = lane & 15, l4 = lane >> 4;

    const s16x8 zero8 = {0, 0, 0, 0, 0, 0, 0, 0};

    if (tid < S_) ids[tid] = inputs[b * S_ + tid];
    for (int c = tid; c < (128 * HTS) / 8; c += 256) ((s16x8*)HT)[c] = zero8;
    if (tid < 32) ((s16x8*)hl)[70 * 16 + tid] = zero8;
    __syncthreads();

    #pragma unroll
    for (int it = 0; it < 5; ++it) {
        int idx = it * 256 + tid;
        if (idx < S_ * 16) {
            int s = idx >> 4, c8 = idx & 15;
            const float4* ev = (const float4*)(emb + (long)ids[s] * D_ + c8 * 8);
            float4 e0 = ev[0], e1 = ev[1];
            s16x8 p;
            p[0] = (short)f2bf(e0.x); p[1] = (short)f2bf(e0.y);
            p[2] = (short)f2bf(e0.z); p[3] = (short)f2bf(e0.w);
            p[4] = (short)f2bf(e1.x); p[5] = (short)f2bf(e1.y);
            p[6] = (short)f2bf(e1.z); p[7] = (short)f2bf(e1.w);
            ((s16x8*)hl)[s * 16 + (c8 ^ (s & 7))] = p;
            #pragma unroll
            for (int e = 0; e < 8; ++e) {
                int d = c8 * 8 + e;
                HT[d * HTS + s] = (unsigned short)p[e];
            }
        }
    }
    __syncthreads();

    s16x8 af_all[4][4];
    {
        const float* aptr[4] = {a0p, a1p, a2p, a3p};
        int hrow = i0 + l15;
        #pragma unroll
        for (int ks = 0; ks < 4; ++ks) {
            s16x8 hf = ((s16x8*)hl)[hrow * 16 + ((ks * 4 + l4) ^ (hrow & 7))];
            #pragma unroll
            for (int r = 0; r < 4; ++r) {
                const float* ar = aptr[r];
                float4 alo = *(const float4*)(ar + ks * 32 + l4 * 8);
                float4 ahi = *(const float4*)(ar + ks * 32 + l4 * 8 + 4);
                s16x8 o;
                o[0] = (short)f2bf(bf2f((unsigned short)hf[0]) * alo.x);
                o[1] = (short)f2bf(bf2f((unsigned short)hf[1]) * alo.y);
                o[2] = (short)f2bf(bf2f((unsigned short)hf[2]) * alo.z);
                o[3] = (short)f2bf(bf2f((unsigned short)hf[3]) * alo.w);
                o[4] = (short)f2bf(bf2f((unsigned short)hf[4]) * ahi.x);
                o[5] = (short)f2bf(bf2f((unsigned short)hf[5]) * ahi.y);
                o[6] = (short)f2bf(bf2f((unsigned short)hf[6]) * ahi.z);
                o[7] = (short)f2bf(bf2f((unsigned short)hf[7]) * ahi.w);
                af_all[r][ks] = o;
            }
        }
    }

    for (int n = wave; n < 5; n += 4) {
        s16x8 bfr[4];
        int jr = n * 16 + l15;
        int jrc = jr < 72 ? jr : 71;
        #pragma unroll
        for (int ks = 0; ks < 4; ++ks)
            bfr[ks] = ((s16x8*)hl)[jrc * 16 + ((ks * 4 + l4) ^ (jrc & 7))];

        f32x4 ac0 = {0.f,0.f,0.f,0.f}, ac1 = {0.f,0.f,0.f,0.f};
        f32x4 ac2 = {0.f,0.f,0.f,0.f}, ac3 = {0.f,0.f,0.f,0.f};
        #pragma unroll
        for (int ks = 0; ks < 4; ++ks) {
            ac0 = __builtin_amdgcn_mfma_f32_16x16x32_bf16(af_all[0][ks], bfr[ks], ac0, 0, 0, 0);
            ac1 = __builtin_amdgcn_mfma_f32_16x16x32_bf16(af_all[1][ks], bfr[ks], ac1, 0, 0, 0);
            ac2 = __builtin_amdgcn_mfma_f32_16x16x32_bf16(af_all[2][ks], bfr[ks], ac2, 0, 0, 0);
            ac3 = __builtin_amdgcn_mfma_f32_16x16x32_bf16(af_all[3][ks], bfr[ks], ac3, 0, 0, 0);
        }

        #pragma unroll
        for (int reg = 0; reg < 4; ++reg) {
            int il = l4 * 4 + reg;
            int i  = i0 + il;
            int j  = n * 16 + l15;
            float v;
            if (j < S_) {
                int ic = i < S_ ? i : S_ - 1;
                int a  = adj[((long)b * S_ + ic) * S_ + j];
                float raw = (a == 1) ? ac0[reg] : (a == 2) ? ac1[reg]
                          : (a == 3) ? ac2[reg] : (a == 4) ? ac3[reg] : 0.f;
                v = (a >= 1 && a <= 4) ? (raw > 0.f ? raw : 0.2f * raw) : -9e15f;
            } else {
                v = -INFINITY;
            }
            El[il * 84 + j] = v;
        }
    }
    __syncthreads();

    {
        int g = tid >> 4, li = tid & 15;
        float mx = -INFINITY;
        for (int j = li; j < S_; j += 16) mx = fmaxf(mx, El[g * 84 + j]);
        #pragma unroll
        for (int o = 1; o < 16; o <<= 1) mx = fmaxf(mx, __shfl_xor(mx, o));
        float sm = 0.f;
        for (int j = li; j < S_; j += 16) {
            float ex = __expf(El[g * 84 + j] - mx);
            El[g * 84 + j] = ex;
            sm += ex;
        }
        #pragma unroll
        for (int o = 1; o < 16; o <<= 1) sm += __shfl_xor(sm, o);
        float inv = 1.f / sm;
        for (int j = li; j < 104; j += 16)
            al[g * 104 + j] = (j < S_) ? f2bf(El[g * 84 + j] * inv) : (unsigned short)0;
    }
    __syncthreads();

    for (int n = wave; n < 8; n += 4) {
        f32x4 acc = {0.f, 0.f, 0.f, 0.f};
        int d = n * 16 + l15;
        #pragma unroll
        for (int ks = 0; ks < 3; ++ks) {
            s16x8 afp = *(const s16x8*)(al + l15 * 104 + ks * 32 + l4 * 8);
            s16x8 bfp = *(const s16x8*)(HT + d * HTS + ks * 32 + l4 * 8);
            acc = __builtin_amdgcn_mfma_f32_16x16x32_bf16(afp, bfp, acc, 0, 0, 0);
        }
        #pragma unroll
        for (int reg = 0; reg < 4; ++reg) {
            int il = l4 * 4 + reg;
            if (il < IBLK)
                out[((long)b * S_ + (i0 + il)) * D_ + d] = acc[reg];
        }
    }
}

// ---------------- h_global: per-b MFMA neighbor aggregation, sess folded into B ----------------
__global__ __launch_bounds__(256, 3) void global_kernel(
        const int* __restrict__ inputs, const int* __restrict__ adj_all,
        const float* __restrict__ num_w, const float* __restrict__ emb,
        const float* __restrict__ sess,
        const unsigned short* __restrict__ gw1T, const float* __restrict__ gw1,
        const float* __restrict__ gw2,
        const unsigned short* __restrict__ gw3T, const float* __restrict__ gbias,
        float* __restrict__ out) {
    __shared__ __align__(16) unsigned short nv[NRP * 128];   // raw emb[neigh] bf16, swz: 32 KiB
    __shared__ __align__(16) unsigned short cat[16 * 256];   // 8 KiB
    __shared__ int   neigh[NR2];
    __shared__ float nw[NR2];
    __shared__ float spart[NRP][4];
    __shared__ float score[NR2];
    __shared__ float wsm[NR2];

    const int tid  = threadIdx.x;
    const int lane = tid & 63, wave = tid >> 6;
    const int l15  = lane & 15, l4 = lane >> 4;
    const int b    = blockIdx.x;
    const int i0   = blockIdx.y * NPOS;
    const int bs0  = b * S_ + i0;

    const s16x8 zero8 = {0, 0, 0, 0, 0, 0, 0, 0};

    // ---- phase A: neighbor ids + weights, zero pad rows 120..127 ----
    if (tid < NR2) {
        int p = tid / NSAMP;
        int k = tid - p * NSAMP;
        int node = inputs[bs0 + p];
        neigh[tid] = adj_all[node * NSAMP + k];
        nw[tid]    = num_w[node * NSAMP + k];
    }
    if (tid < 128) ((s16x8*)nv)[NR2 * 16 + tid] = zero8;
    __syncthreads();

    // ---- phase B: stage nv = bf16(emb[neigh]) swizzled (no sess multiply) ----
    #pragma unroll
    for (int it = 0; it < 8; ++it) {
        int idx = it * 256 + tid;
        if (idx < NR2 * 16) {
            int row = idx >> 4, c8 = idx & 15;
            const float4* ev = (const float4*)(emb + (long)neigh[row] * D_ + c8 * 8);
            float4 e0 = ev[0], e1 = ev[1];
            s16x8 p;
            p[0] = (short)f2bf(e0.x); p[1] = (short)f2bf(e0.y);
            p[2] = (short)f2bf(e0.z); p[3] = (short)f2bf(e0.w);
            p[4] = (short)f2bf(e1.x); p[5] = (short)f2bf(e1.y);
            p[6] = (short)f2bf(e1.z); p[7] = (short)f2bf(e1.w);
            ((s16x8*)nv)[row * 16 + (c8 ^ (row & 7))] = p;
        }
    }
    __syncthreads();

    // ---- phase C: B-fragments with sess folded: bf' = bf16(sess[r] * gw1[r][c]) ----
    s16x8 bfp[2][4];
    #pragma unroll
    for (int n = 0; n < 2; ++n) {
        int c = (wave * 2 + n) * 16 + l15;
        #pragma unroll
        for (int ks = 0; ks < 4; ++ks) {
            s16x8 g = *(const s16x8*)(gw1T + c * 128 + ks * 32 + l4 * 8);
            float4 slo = *(const float4*)(sess + b * D_ + ks * 32 + l4 * 8);
            float4 shi = *(const float4*)(sess + b * D_ + ks * 32 + l4 * 8 + 4);
            s16x8 o;
            o[0] = (short)f2bf(bf2f((unsigned short)g[0]) * slo.x);
            o[1] = (short)f2bf(bf2f((unsigned short)g[1]) * slo.y);
            o[2] = (short)f2bf(bf2f((unsigned short)g[2]) * slo.z);
            o[3] = (short)f2bf(bf2f((unsigned short)g[3]) * slo.w);
            o[4] = (short)f2bf(bf2f((unsigned short)g[4]) * shi.x);
            o[5] = (short)f2bf(bf2f((unsigned short)g[5]) * shi.y);
            o[6] = (short)f2bf(bf2f((unsigned short)g[6]) * shi.z);
            o[7] = (short)f2bf(bf2f((unsigned short)g[7]) * shi.w);
            bfp[n][ks] = o;
        }
    }
    float g128a = gw1[128 * 128 + wave * 32 + l15];
    float g128b = gw1[128 * 128 + wave * 32 + 16 + l15];
    float gw2a  = gw2[wave * 32 + l15];
    float gw2b  = gw2[wave * 32 + 16 + l15];

    // ---- phase D: gw1 matmul over 8 M-tiles + score epilogue ----
    for (int m = 0; m < NRP / 16; ++m) {
        int arow = m * 16 + l15;
        s16x8 af[4];
        #pragma unroll
        for (int ks = 0; ks < 4; ++ks)
            af[ks] = ((s16x8*)nv)[arow * 16 + ((ks * 4 + l4) ^ (arow & 7))];

        f32x4 acc0 = {0.f, 0.f, 0.f, 0.f}, acc1 = {0.f, 0.f, 0.f, 0.f};
        #pragma unroll
        for (int ks = 0; ks < 4; ++ks) {
            acc0 = __builtin_amdgcn_mfma_f32_16x16x32_bf16(af[ks], bfp[0][ks], acc0, 0, 0, 0);
            acc1 = __builtin_amdgcn_mfma_f32_16x16x32_bf16(af[ks], bfp[1][ks], acc1, 0, 0, 0);
        }

        float sp[4];
        #pragma unroll
        for (int reg = 0; reg < 4; ++reg) {
            int r = m * 16 + l4 * 4 + reg;
            float nwv = (r < NR2) ? nw[r] : 0.f;
            float al0 = acc0[reg] + nwv * g128a;
            float al1 = acc1[reg] + nwv * g128b;
            al0 = al0 > 0.f ? al0 : 0.2f * al0;
            al1 = al1 > 0.f ? al1 : 0.2f * al1;
            sp[reg] = al0 * gw2a + al1 * gw2b;
        }
        #pragma unroll
        for (int off = 1; off < 16; off <<= 1) {
            #pragma unroll
            for (int reg = 0; reg < 4; ++reg) sp[reg] += __shfl_xor(sp[reg], off);
        }
        if (l15 == 0) {
            int rb = m * 16 + l4 * 4;
            #pragma unroll
            for (int reg = 0; reg < 4; ++reg) spart[rb + reg][wave] = sp[reg];
        }
    }
    __syncthreads();

    if (tid < NR2)
        score[tid] = spart[tid][0] + spart[tid][1] + spart[tid][2] + spart[tid][3];
    __syncthreads();

    // ---- softmax over k per position ----
    if (tid < NPOS) {
        float mx = -1e30f;
        #pragma unroll
        for (int k = 0; k < NSAMP; ++k) mx = fmaxf(mx, score[tid * NSAMP + k]);
        float ex[NSAMP]; float ss = 0.f;
        #pragma unroll
        for (int k = 0; k < NSAMP; ++k) { ex[k] = __expf(score[tid * NSAMP + k] - mx); ss += ex[k]; }
        float inv = 1.f / ss;
        #pragma unroll
        for (int k = 0; k < NSAMP; ++k) wsm[tid * NSAMP + k] = ex[k] * inv;
    }
    __syncthreads();

    // ---- phase E: nagg from LDS nv + cat staging ----
    {
        int p  = tid >> 4;           // 0..15 (>=NPOS are pad rows)
        int c8 = tid & 15;
        if (p < NPOS) {
            float a0v[4] = {0.f,0.f,0.f,0.f}, a1v[4] = {0.f,0.f,0.f,0.f};
            #pragma unroll
            for (int k = 0; k < NSAMP; ++k) {
                int row = p * NSAMP + k;
                float w = wsm[row];
                s16x8 nvv = ((s16x8*)nv)[row * 16 + (c8 ^ (row & 7))];
                a0v[0] += w * bf2f((unsigned short)nvv[0]);
                a0v[1] += w * bf2f((unsigned short)nvv[1]);
                a0v[2] += w * bf2f((unsigned short)nvv[2]);
                a0v[3] += w * bf2f((unsigned short)nvv[3]);
                a1v[0] += w * bf2f((unsigned short)nvv[4]);
                a1v[1] += w * bf2f((unsigned short)nvv[5]);
                a1v[2] += w * bf2f((unsigned short)nvv[6]);
                a1v[3] += w * bf2f((unsigned short)nvv[7]);
            }
            int node = inputs[bs0 + p];
            const float4* hv = (const float4*)(emb + (long)node * D_ + c8 * 8);
            float4 h0 = hv[0], h1 = hv[1];
            s16x8 ph, pa;
            ph[0]=(short)f2bf(h0.x); ph[1]=(short)f2bf(h0.y); ph[2]=(short)f2bf(h0.z); ph[3]=(short)f2bf(h0.w);
            ph[4]=(short)f2bf(h1.x); ph[5]=(short)f2bf(h1.y); ph[6]=(short)f2bf(h1.z); ph[7]=(short)f2bf(h1.w);
            pa[0]=(short)f2bf(a0v[0]); pa[1]=(short)f2bf(a0v[1]); pa[2]=(short)f2bf(a0v[2]); pa[3]=(short)f2bf(a0v[3]);
            pa[4]=(short)f2bf(a1v[0]); pa[5]=(short)f2bf(a1v[1]); pa[6]=(short)f2bf(a1v[2]); pa[7]=(short)f2bf(a1v[3]);
            ((s16x8*)cat)[p * 32 + ( c8       ^ (p & 7))] = ph;
            ((s16x8*)cat)[p * 32 + ((16 + c8) ^ (p & 7))] = pa;
        } else {
            ((s16x8*)cat)[p * 32 + ( c8       ^ (p & 7))] = zero8;
            ((s16x8*)cat)[p * 32 + ((16 + c8) ^ (p & 7))] = zero8;
        }
    }
    __syncthreads();

    // ---- phase F: gw3 matmul (16x256)@(256x128) + bias + relu ----
    {
        f32x4 acc0 = {0.f,0.f,0.f,0.f}, acc1 = {0.f,0.f,0.f,0.f};
        int arow = l15;
        int cc = wave * 32 + l15;
        #pragma unroll
        for (int ks = 0; ks < 8; ++ks) {
            s16x8 a  = ((s16x8*)cat)[arow * 32 + ((ks * 4 + l4) ^ (arow & 7))];
            s16x8 b0 = *(const s16x8*)(gw3T +  cc       * 256 + ks * 32 + l4 * 8);
            s16x8 b1 = *(const s16x8*)(gw3T + (cc + 16) * 256 + ks * 32 + l4 * 8);
            acc0 = __builtin_amdgcn_mfma_f32_16x16x32_bf16(a, b0, acc0, 0, 0, 0);
            acc1 = __builtin_amdgcn_mfma_f32_16x16x32_bf16(a, b1, acc1, 0, 0, 0);
        }
        float gb0 = gbias[wave * 32 + l15];
        float gb1 = gbias[wave * 32 + 16 + l15];
        #pragma unroll
        for (int reg = 0; reg < 4; ++reg) {
            int il = l4 * 4 + reg;
            if (il < NPOS) {
                long bs = bs0 + il;
                float o0 = acc0[reg] + gb0;
                float o1 = acc1[reg] + gb1;
                out[(long)HGLOB + bs * D_ + wave * 32 + l15]      = o0 > 0.f ? o0 : 0.f;
                out[(long)HGLOB + bs * D_ + wave * 32 + 16 + l15] = o1 > 0.f ? o1 : 0.f;
            }
        }
    }
}

extern "C" void kernel_launch(void* const* d_in, const int* in_sizes, int n_in,
                              void* d_out, int out_size, void* d_ws, size_t ws_size,
                              hipStream_t stream) {
    const int*   inputs  = (const int*)  d_in[0];
    const int*   adj     = (const int*)  d_in[1];
    const int*   mask    = (const int*)  d_in[2];
    const int*   item    = (const int*)  d_in[3];
    const int*   adj_all = (const int*)  d_in[5];
    const float* num_w   = (const float*)d_in[6];
    const float* emb     = (const float*)d_in[7];
    const float* a0      = (const float*)d_in[8];
    const float* a1      = (const float*)d_in[9];
    const float* a2      = (const float*)d_in[10];
    const float* a3      = (const float*)d_in[11];
    const float* gw1     = (const float*)d_in[12];
    const float* gw2     = (const float*)d_in[13];
    const float* gw3     = (const float*)d_in[14];
    const float* gbias   = (const float*)d_in[15];
    float* out = (float*)d_out;

    float*          sess = (float*)d_ws;                              // 131072 B
    unsigned short* gw1T = (unsigned short*)((char*)d_ws + 131072);   // 32768 B
    unsigned short* gw3T = gw1T + 128 * 128;                          // 65536 B

    sess_kernel<<<B_, D_, 0, stream>>>(item, mask, emb, sess);
    pack_weights<<<128, 256, 0, stream>>>(gw1, gw3, gw1T, gw3T);
    local_kernel<<<dim3(B_, 5), 256, 0, stream>>>(inputs, adj, emb, a0, a1, a2, a3, out);
    global_kernel<<<dim3(B_, 7), 256, 0, stream>>>(inputs, adj_all, num_w, emb, sess,
                                                   gw1T, gw1, gw2, gw3T, gbias, out);
}